// Round 7
// baseline (954.705 us; speedup 1.0000x reference)
//
#include <hip/hip_runtime.h>
#include <hip/hip_bf16.h>
#include <math.h>

using short8 = __attribute__((ext_vector_type(8))) short;
using f32x4  = __attribute__((ext_vector_type(4))) float;

#define MFMA_B16(A,B,C) __builtin_amdgcn_mfma_f32_16x16x32_bf16((A),(B),(C),0,0,0)

// ---------------- LDS layout (bytes) ----------------
// Two windows per block. Per window: aln [49][392]u16 (spill reads land in
// later regions: garbage rows only feed discarded C rows / masked scores);
// pool: q2/k2 [49][72], vT2 [64][72] (zero-init, token cols>=49 stay 0),
// oh [64][72]. MLP: hid double-buffer 2x[64][136] aliases the pool.
#define ALN_STR 392
#define ALN_SZ  38416
#define POOL    76832          // = 2*ALN_SZ
#define PS      34816          // per-window pool stride (= 2 hid buffers)
#define QK_STR  72
#define VT_STR  72
#define OH_STR  72
#define HID_STR 136
#define SMEM_BYTES 146464      // 76832 + 2*34816 <= 160 KiB

__device__ __forceinline__ unsigned short f2bfu(float x) {   // RNE f32->bf16
  unsigned u = __float_as_uint(x);
  return (unsigned short)((u + 0x7fffu + ((u >> 16) & 1u)) >> 16);
}
__device__ __forceinline__ unsigned pk2(float a, float b) {
  return (unsigned)f2bfu(a) | ((unsigned)f2bfu(b) << 16);
}

// B-operand load. WBF: packed fragment layout [tile][kchunk][lane][8] bf16 ->
// one coalesced 16B/lane read. !WBF: gather from f32 row-major + convert.
template<bool WBF>
__device__ __forceinline__ short8 loadW(const void* base, int tile, int K8, int kcb,
                                        int l, int row, int ldk, int k0) {
  if constexpr (WBF) {
    return *(const short8*)((const unsigned short*)base +
                            (((size_t)(tile * K8 + kcb)) << 7) + l * 8);
  } else {
    const float* p = (const float*)base + (size_t)row * ldk + k0;
    float4 x = *(const float4*)p;
    float4 y = *(const float4*)(p + 4);
    short8 r;
    r[0]=(short)f2bfu(x.x); r[1]=(short)f2bfu(x.y); r[2]=(short)f2bfu(x.z); r[3]=(short)f2bfu(x.w);
    r[4]=(short)f2bfu(y.x); r[5]=(short)f2bfu(y.y); r[6]=(short)f2bfu(y.z); r[7]=(short)f2bfu(y.w);
    return r;
  }
}

// Repack f32 [rows][K] -> bf16 fragment order [tile][kc][r16][8].
__global__ void cvt_pack(const float* __restrict__ src, unsigned short* __restrict__ dst,
                         int K, int n) {
  int K8 = K >> 3;
  int i = blockIdx.x * blockDim.x + threadIdx.x;
  if (i >= n) return;
  int e = i & 7;
  int idx = i >> 3;
  int r = idx & 15; idx >>= 4;
  int kc = idx % K8, ci = idx / K8;
  dst[i] = f2bfu(src[(size_t)(ci * 16 + r) * K + kc * 8 + e]);
}

template<bool WBF>
__global__ __launch_bounds__(1024, 4)
void swin_mfma(const float* __restrict__ tokens,
               const void* __restrict__ ipw,  const float* __restrict__ ipb,
               const void* __restrict__ outw, const float* __restrict__ outb,
               const float* __restrict__ ln1g, const float* __restrict__ ln1b,
               const void* __restrict__ w1,   const float* __restrict__ b1,
               const void* __restrict__ w2,   const float* __restrict__ b2,
               const float* __restrict__ ln2g, const float* __restrict__ ln2b,
               float* __restrict__ out)
{
  extern __shared__ char smem[];
  const int tid = threadIdx.x;
  const int win = tid >> 9;            // which of the 2 windows this thread serves
  const int wv  = (tid >> 6) & 7;      // wave id within window group (0..7)
  const int l   = tid & 63;
  const int cl  = l & 15, kg = l >> 4;
  const int wid = blockIdx.x * 2 + win;
  const int iw = wid & 7, ih = (wid >> 3) & 7, bt = wid >> 6;

  unsigned short* aln = (unsigned short*)(smem + win * ALN_SZ);
  char* pool = smem + POOL + win * PS;
  unsigned short* q2   = (unsigned short*)(pool);
  unsigned short* k2   = (unsigned short*)(pool + 7056);
  unsigned short* vT2  = (unsigned short*)(pool + 14112);
  unsigned short* oh   = (unsigned short*)(pool + 23328);
  unsigned short* hid0 = (unsigned short*)(pool);
  unsigned short* hid1 = (unsigned short*)(pool + 17408);

  auto gidx = [&](int r, int c) -> size_t {
    int wi = r / 7, wj = r - wi * 7;
    return ((size_t)bt * 3136 + (size_t)((ih*7 + wi) * 56 + iw*7 + wj)) * 384 + c;
  };

  auto ln_pass = [&](const float* src, const float* gw, const float* gb) {
    int row = (tid >> 3) & 63, lj = tid & 7;   // (tid>>3)>>6 == win: consistent
    if (row < 49) {
      size_t base = gidx(row, 0);
      float4 xv[12];
      float sx = 0.f, sxx = 0.f;
      #pragma unroll
      for (int k = 0; k < 12; ++k) {
        xv[k] = *(const float4*)&src[base + (lj + 8*k) * 4];
        sx  += xv[k].x + xv[k].y + xv[k].z + xv[k].w;
        sxx += xv[k].x*xv[k].x + xv[k].y*xv[k].y + xv[k].z*xv[k].z + xv[k].w*xv[k].w;
      }
      #pragma unroll
      for (int d = 1; d < 8; d <<= 1) { sx += __shfl_xor(sx, d, 8); sxx += __shfl_xor(sxx, d, 8); }
      float mean = sx * (1.f/384.f);
      float rs = rsqrtf(sxx * (1.f/384.f) - mean*mean + 1e-5f);
      unsigned short* arow = aln + row * ALN_STR;
      #pragma unroll
      for (int k = 0; k < 12; ++k) {
        int c = (lj + 8*k) * 4;
        float4 gv = *(const float4*)&gw[c];
        float4 bv = *(const float4*)&gb[c];
        unsigned u0 = pk2((xv[k].x-mean)*rs*gv.x + bv.x, (xv[k].y-mean)*rs*gv.y + bv.y);
        unsigned u1 = pk2((xv[k].z-mean)*rs*gv.z + bv.z, (xv[k].w-mean)*rs*gv.w + bv.w);
        *(uint2*)&arow[c] = make_uint2(u0, u1);
      }
    }
  };

  const int ri = wv & 3;               // wave's row-tile (tokens 16ri..16ri+15)
  const int ch = wv >> 2;              // wave's column half
  const int arow0 = (cl + 16 * ri) * ALN_STR;

  // QKV for head pair pr: writes q2/k2/vT2 (rows<49 only). A from LDS (ratio 3).
  auto qkv = [&](int pr) {
    #pragma unroll
    for (int half = 0; half < 2; ++half) {
      int tilea[3], growa[3], parta[3], wta[3];
      #pragma unroll
      for (int j = 0; j < 3; ++j) {
        int ci = ch + 2 * (half * 3 + j);
        parta[j] = ci >> 2; wta[j] = ci & 3;
        tilea[j] = parta[j] * 24 + pr * 4 + wta[j];
        growa[j] = parta[j] * 384 + pr * 64 + wta[j] * 16 + cl;
      }
      f32x4 d0{0,0,0,0}, d1{0,0,0,0}, d2{0,0,0,0};
      #pragma unroll
      for (int kt = 0; kt < 12; ++kt) {
        int k0 = kt * 32 + kg * 8;
        short8 a  = *(const short8*)&aln[arow0 + k0];
        short8 b0 = loadW<WBF>(ipw, tilea[0], 48, kt*4, l, growa[0], 384, k0);
        short8 bb1 = loadW<WBF>(ipw, tilea[1], 48, kt*4, l, growa[1], 384, k0);
        short8 bb2 = loadW<WBF>(ipw, tilea[2], 48, kt*4, l, growa[2], 384, k0);
        d0 = MFMA_B16(a, b0, d0);
        d1 = MFMA_B16(a, bb1, d1);
        d2 = MFMA_B16(a, bb2, d2);
      }
      #pragma unroll
      for (int j = 0; j < 3; ++j) {
        f32x4 dd = (j == 0) ? d0 : (j == 1) ? d1 : d2;
        int within = wta[j] * 16 + cl;
        float bias = ipb[growa[j]];
        float scl = (parta[j] == 0) ? 0.17677669529663687f : 1.f;
        #pragma unroll
        for (int rg = 0; rg < 4; ++rg) {
          int row = kg * 4 + rg + 16 * ri;
          if (row < 49) {
            unsigned short bv = f2bfu((dd[rg] + bias) * scl);
            if      (parta[j] == 0) q2[row * QK_STR + within] = bv;
            else if (parta[j] == 1) k2[row * QK_STR + within] = bv;
            else                    vT2[within * VT_STR + row] = bv;
          }
        }
      }
    }
  };

  // ---- init: zero vT2 pad (token cols >=49 must stay 0), LN1 ----
  for (int i = (tid & 511); i < (64*VT_STR)/2; i += 512)
    ((unsigned*)(pool + 14112))[i] = 0u;
  ln_pass(tokens, ln1g, ln1b);
  __syncthreads();

  // out-proj accumulator: wave (ri, ch) owns row-tile ri x 12 col-tiles
  f32x4 opacc[12];
  #pragma unroll
  for (int j = 0; j < 12; ++j) opacc[j] = f32x4{0.f,0.f,0.f,0.f};

  qkv(0);
  __syncthreads();

  const int hl = wv & 1, qci = wv >> 1;   // wave's (head-within-pair, q col-tile)

  for (int pr = 0; pr < 6; ++pr) {
    // ---- P_a: scores (swapped: mfma(K,Q)) + in-register softmax + PV ----
    {
      short8 bq = *(const short8*)&q2[(16*qci + cl) * QK_STR + hl*32 + kg*8];
      f32x4 dsc[4];
      #pragma unroll
      for (int kri = 0; kri < 4; ++kri) {
        short8 ak = *(const short8*)&k2[(16*kri + cl) * QK_STR + hl*32 + kg*8];
        f32x4 z{0.f,0.f,0.f,0.f};
        dsc[kri] = MFMA_B16(ak, bq, z);
      }
      // lane (cl,kg) holds scores(k=16kri+4kg+r, q=16qci+cl); mask k>=49
      float ev[4][4];
      float mx = -1e30f;
      #pragma unroll
      for (int kri = 0; kri < 4; ++kri)
        #pragma unroll
        for (int r = 0; r < 4; ++r) {
          int kidx = 16*kri + 4*kg + r;
          float v = (kidx < 49) ? dsc[kri][r] : -1e30f;
          ev[kri][r] = v;
          mx = fmaxf(mx, v);
        }
      mx = fmaxf(mx, __shfl_xor(mx, 16));
      mx = fmaxf(mx, __shfl_xor(mx, 32));
      float sum = 0.f;
      #pragma unroll
      for (int kri = 0; kri < 4; ++kri)
        #pragma unroll
        for (int r = 0; r < 4; ++r) {
          float e = __expf(ev[kri][r] - mx);
          ev[kri][r] = e; sum += e;
        }
      sum += __shfl_xor(sum, 16);
      sum += __shfl_xor(sum, 32);
      float inv = 1.f / sum;
      unsigned pk[4][2];
      #pragma unroll
      for (int kri = 0; kri < 4; ++kri) {
        pk[kri][0] = pk2(ev[kri][0]*inv, ev[kri][1]*inv);
        pk[kri][1] = pk2(ev[kri][2]*inv, ev[kri][3]*inv);
      }
      // PV (swapped: mfma(vT, P)) -> oh^T; P B-frags built by shuffles
      f32x4 dot0{0.f,0.f,0.f,0.f}, dot1{0.f,0.f,0.f,0.f};
      const int sA = cl + 32 * (kg & 1);
      const bool hi = (kg >> 1) & 1;
      #pragma unroll
      for (int kt = 0; kt < 2; ++kt) {
        unsigned x0 = (unsigned)__shfl((int)pk[2*kt][0],   sA);
        unsigned x1 = (unsigned)__shfl((int)pk[2*kt][1],   sA);
        unsigned x2 = (unsigned)__shfl((int)pk[2*kt][0],   sA + 16);
        unsigned x3 = (unsigned)__shfl((int)pk[2*kt][1],   sA + 16);
        unsigned y0 = (unsigned)__shfl((int)pk[2*kt+1][0], sA);
        unsigned y1 = (unsigned)__shfl((int)pk[2*kt+1][1], sA);
        unsigned y2 = (unsigned)__shfl((int)pk[2*kt+1][0], sA + 16);
        unsigned y3 = (unsigned)__shfl((int)pk[2*kt+1][1], sA + 16);
        uint4 bu = make_uint4(hi ? y0 : x0, hi ? y1 : x1, hi ? y2 : x2, hi ? y3 : x3);
        short8 bfrag = *(short8*)&bu;
        short8 a0 = *(const short8*)&vT2[(hl*32 +  0 + cl) * VT_STR + kt*32 + kg*8];
        short8 a1 = *(const short8*)&vT2[(hl*32 + 16 + cl) * VT_STR + kt*32 + kg*8];
        dot0 = MFMA_B16(a0, bfrag, dot0);
        dot1 = MFMA_B16(a1, bfrag, dot1);
      }
      int q = 16*qci + cl;
      if (q < 49) {
        int base = q * OH_STR + hl*32 + kg*4;
        *(unsigned*)&oh[base     ] = pk2(dot0[0], dot0[1]);
        *(unsigned*)&oh[base +  2] = pk2(dot0[2], dot0[3]);
        *(unsigned*)&oh[base + 16] = pk2(dot1[0], dot1[1]);
        *(unsigned*)&oh[base + 18] = pk2(dot1[2], dot1[3]);
      }
    }
    __syncthreads();

    // ---- P_b: out-proj(pr): wave = row-tile ri x 12 col-tiles, K=64 ----
    {
      short8 ao0 = *(const short8*)&oh[(cl + 16*ri) * OH_STR +      kg*8];
      short8 ao1 = *(const short8*)&oh[(cl + 16*ri) * OH_STR + 32 + kg*8];
      #pragma unroll
      for (int j = 0; j < 12; ++j) {
        int ct = ch*12 + j;
        short8 bw0 = loadW<WBF>(outw, ct, 48, pr*8,     l, ct*16 + cl, 384, pr*64      + kg*8);
        short8 bw1 = loadW<WBF>(outw, ct, 48, pr*8 + 4, l, ct*16 + cl, 384, pr*64 + 32 + kg*8);
        opacc[j] = MFMA_B16(ao0, bw0, opacc[j]);
        opacc[j] = MFMA_B16(ao1, bw1, opacc[j]);
      }
      if (pr < 5) qkv(pr + 1);
    }
    __syncthreads();
  }

  // ---- win = tokens + attn + out_b -> out  (wave: row-tile ri x 12 tiles) ----
  #pragma unroll
  for (int j = 0; j < 12; ++j) {
    int col = (ch*12 + j) * 16 + cl;
    float ob = outb[col];
    #pragma unroll
    for (int rg = 0; rg < 4; ++rg) {
      int row = 16*ri + kg*4 + rg;
      if (row < 49) {
        size_t g = gidx(row, col);
        out[g] = tokens[g] + opacc[j][rg] + ob;
      }
    }
  }
  __syncthreads();

  // ---- LN2 ----
  ln_pass(out, ln2g, ln2b);
  __syncthreads();

  // ---- MLP: aln A-fragments in registers (48 VGPR), hid double-buffered ----
  short8 alnA[12];
  #pragma unroll
  for (int kt = 0; kt < 12; ++kt)
    alnA[kt] = *(const short8*)&aln[arow0 + kt*32 + kg*8];

  f32x4 macc[12];
  #pragma unroll
  for (int j = 0; j < 12; ++j) macc[j] = f32x4{0.f,0.f,0.f,0.f};

  // MLP1(cc): wave = row-tile ri x 4 col-tiles (ch quarter of 128 cols), A in reg
  auto mlp1 = [&](int cc, unsigned short* hb) {
    f32x4 e0{0,0,0,0}, e1{0,0,0,0}, e2{0,0,0,0}, e3{0,0,0,0};
    #pragma unroll
    for (int kt = 0; kt < 12; ++kt) {
      int k0 = kt*32 + kg*8;
      short8 wb0 = loadW<WBF>(w1, cc*8 + ch*4 + 0, 48, kt*4, l, (cc*8+ch*4+0)*16 + cl, 384, k0);
      short8 wb1 = loadW<WBF>(w1, cc*8 + ch*4 + 1, 48, kt*4, l, (cc*8+ch*4+1)*16 + cl, 384, k0);
      short8 wb2 = loadW<WBF>(w1, cc*8 + ch*4 + 2, 48, kt*4, l, (cc*8+ch*4+2)*16 + cl, 384, k0);
      short8 wb3 = loadW<WBF>(w1, cc*8 + ch*4 + 3, 48, kt*4, l, (cc*8+ch*4+3)*16 + cl, 384, k0);
      e0 = MFMA_B16(alnA[kt], wb0, e0);
      e1 = MFMA_B16(alnA[kt], wb1, e1);
      e2 = MFMA_B16(alnA[kt], wb2, e2);
      e3 = MFMA_B16(alnA[kt], wb3, e3);
    }
    #pragma unroll
    for (int j = 0; j < 4; ++j) {
      f32x4 ee = (j == 0) ? e0 : (j == 1) ? e1 : (j == 2) ? e2 : e3;
      int n = cc*128 + ch*64 + j*16 + cl;
      float bb = b1[n];
      #pragma unroll
      for (int rg = 0; rg < 4; ++rg) {
        int row = 16*ri + kg*4 + rg;
        if (row < 49) {
          float x = ee[rg] + bb;
          // gelu(x) ~= x * sigmoid(1.5957691(x + 0.044715 x^3))
          float t2 = 0.044715f * x * x;
          float arg = __builtin_fmaf(t2, x, x);
          float e = __expf(1.5957691216f * arg);
          float gl = x * (e / (e + 1.f));
          hb[row * HID_STR + ch*64 + j*16 + cl] = f2bfu(gl);
        }
      }
    }
  };
  // MLP2(cc): wave = row-tile ri x 12 col-tiles, K=128 (1 A-read per kt)
  auto mlp2 = [&](int cc, const unsigned short* hb) {
    #pragma unroll
    for (int kt = 0; kt < 4; ++kt) {
      short8 hd = *(const short8*)&hb[(cl + 16*ri) * HID_STR + kt*32 + kg*8];
      #pragma unroll
      for (int j = 0; j < 12; ++j) {
        int ct = ch*12 + j;
        short8 bw = loadW<WBF>(w2, ct, 192, cc*16 + kt*4, l,
                               ct*16 + cl, 1536, cc*128 + kt*32 + kg*8);
        macc[j] = MFMA_B16(hd, bw, macc[j]);
      }
    }
  };

  mlp1(0, hid0);
  __syncthreads();
  for (int cc = 1; cc < 12; ++cc) {
    mlp2(cc - 1, ((cc - 1) & 1) ? hid1 : hid0);
    mlp1(cc, (cc & 1) ? hid1 : hid0);
    __syncthreads();
  }
  mlp2(11, hid1);

  // ---- final: out += mlp + b2 ----
  #pragma unroll
  for (int j = 0; j < 12; ++j) {
    int col = (ch*12 + j) * 16 + cl;
    float bb2 = b2[col];
    #pragma unroll
    for (int rg = 0; rg < 4; ++rg) {
      int row = 16*ri + kg*4 + rg;
      if (row < 49) {
        size_t g = gidx(row, col);
        out[g] = out[g] + macc[j][rg] + bb2;
      }
    }
  }
}

// ws layout (bf16 elements): ipw[442368] | outw[147456] | w1[589824] | w2[589824]
#define WS_IPW  0
#define WS_OUTW 442368
#define WS_W1   589824
#define WS_W2   1179648
#define WS_TOT  1769472

extern "C" void kernel_launch(void* const* d_in, const int* in_sizes, int n_in,
                              void* d_out, int out_size, void* d_ws, size_t ws_size,
                              hipStream_t stream) {
  (void)in_sizes; (void)n_in; (void)out_size;
  const float* tokens = (const float*)d_in[0];
  const float* ipw  = (const float*)d_in[1];
  const float* ipb  = (const float*)d_in[2];
  const float* outw = (const float*)d_in[3];
  const float* outb = (const float*)d_in[4];
  const float* ln1g = (const float*)d_in[5];
  const float* ln1b = (const float*)d_in[6];
  const float* w1   = (const float*)d_in[7];
  const float* b1   = (const float*)d_in[8];
  const float* w2   = (const float*)d_in[9];
  const float* b2   = (const float*)d_in[10];
  const float* ln2g = (const float*)d_in[11];
  const float* ln2b = (const float*)d_in[12];
  float* out = (float*)d_out;

  bool wbf = (ws_size >= (size_t)WS_TOT * 2);
  if (wbf) {
    unsigned short* wsp = (unsigned short*)d_ws;
    hipLaunchKernelGGL(cvt_pack, dim3((442368+511)/512), dim3(512), 0, stream, ipw,  wsp + WS_IPW,  384,  442368);
    hipLaunchKernelGGL(cvt_pack, dim3((147456+511)/512), dim3(512), 0, stream, outw, wsp + WS_OUTW, 384,  147456);
    hipLaunchKernelGGL(cvt_pack, dim3((589824+511)/512), dim3(512), 0, stream, w1,   wsp + WS_W1,   384,  589824);
    hipLaunchKernelGGL(cvt_pack, dim3((589824+511)/512), dim3(512), 0, stream, w2,   wsp + WS_W2,   1536, 589824);
    (void)hipFuncSetAttribute((const void*)swin_mfma<true>,
                              hipFuncAttributeMaxDynamicSharedMemorySize, SMEM_BYTES);
    hipLaunchKernelGGL((swin_mfma<true>), dim3(512), dim3(1024), SMEM_BYTES, stream,
                       tokens, (const void*)(wsp + WS_IPW), ipb,
                       (const void*)(wsp + WS_OUTW), outb, ln1g, ln1b,
                       (const void*)(wsp + WS_W1), b1, (const void*)(wsp + WS_W2), b2,
                       ln2g, ln2b, out);
  } else {
    (void)hipFuncSetAttribute((const void*)swin_mfma<false>,
                              hipFuncAttributeMaxDynamicSharedMemorySize, SMEM_BYTES);
    hipLaunchKernelGGL((swin_mfma<false>), dim3(512), dim3(1024), SMEM_BYTES, stream,
                       tokens, (const void*)ipw, ipb, (const void*)outw, outb, ln1g, ln1b,
                       (const void*)w1, b1, (const void*)w2, b2, ln2g, ln2b, out);
  }
}

// Round 8
// 537.686 us; speedup vs baseline: 1.7756x; 1.7756x over previous
//
#include <hip/hip_runtime.h>
#include <hip/hip_bf16.h>
#include <math.h>

using short8 = __attribute__((ext_vector_type(8))) short;
using f32x4  = __attribute__((ext_vector_type(4))) float;

#define MFMA_B16(A,B,C) __builtin_amdgcn_mfma_f32_16x16x32_bf16((A),(B),(C),0,0,0)

// ---------------- LDS layout (bytes) ----------------
// Two windows per block. Per window: aln [49][392]u16 (spill reads land in
// later regions: garbage rows only feed discarded C rows / masked scores);
// pool: q2/k2 [49][72], vT2 [64][72] (zero-init, token cols>=49 stay 0),
// oh [64][72]. MLP: hid double-buffer 2x[64][136] aliases the pool.
#define ALN_STR 392
#define ALN_SZ  38416
#define POOL    76832          // = 2*ALN_SZ
#define PS      34816          // per-window pool stride (= 2 hid buffers)
#define Q2_OFF  0
#define K2_OFF  7056
#define VT_OFF  14112
#define OH_OFF  23328
#define HIDB    17408          // hid buffer stride (bytes)
#define QK_STR  72
#define VT_STR  72
#define OH_STR  72
#define HID_STR 136
#define SMEM_BYTES 146464      // 76832 + 2*34816 <= 160 KiB

__device__ __forceinline__ unsigned short f2bfu(float x) {   // RNE f32->bf16
  unsigned u = __float_as_uint(x);
  return (unsigned short)((u + 0x7fffu + ((u >> 16) & 1u)) >> 16);
}
__device__ __forceinline__ unsigned pk2(float a, float b) {
  return (unsigned)f2bfu(a) | ((unsigned)f2bfu(b) << 16);
}

// B-operand load. WBF: packed fragment layout [tile][kchunk][lane][8] bf16 ->
// one coalesced 16B/lane read. !WBF: gather from f32 row-major + convert.
template<bool WBF>
__device__ __forceinline__ short8 loadW(const void* base, int tile, int K8, int kcb,
                                        int l, int row, int ldk, int k0) {
  if constexpr (WBF) {
    return *(const short8*)((const unsigned short*)base +
                            (((size_t)(tile * K8 + kcb)) << 7) + l * 8);
  } else {
    const float* p = (const float*)base + (size_t)row * ldk + k0;
    float4 x = *(const float4*)p;
    float4 y = *(const float4*)(p + 4);
    short8 r;
    r[0]=(short)f2bfu(x.x); r[1]=(short)f2bfu(x.y); r[2]=(short)f2bfu(x.z); r[3]=(short)f2bfu(x.w);
    r[4]=(short)f2bfu(y.x); r[5]=(short)f2bfu(y.y); r[6]=(short)f2bfu(y.z); r[7]=(short)f2bfu(y.w);
    return r;
  }
}

// Repack f32 [rows][K] -> bf16 fragment order [tile][kc][r16][8].
__global__ void cvt_pack(const float* __restrict__ src, unsigned short* __restrict__ dst,
                         int K, int n) {
  int K8 = K >> 3;
  int i = blockIdx.x * blockDim.x + threadIdx.x;
  if (i >= n) return;
  int e = i & 7;
  int idx = i >> 3;
  int r = idx & 15; idx >>= 4;
  int kc = idx % K8, ci = idx / K8;
  dst[i] = f2bfu(src[(size_t)(ci * 16 + r) * K + kc * 8 + e]);
}

template<bool WBF>
__global__ __launch_bounds__(1024, 4)
void swin_mfma(const float* __restrict__ tokens,
               const void* __restrict__ ipw,  const float* __restrict__ ipb,
               const void* __restrict__ outw, const float* __restrict__ outb,
               const float* __restrict__ ln1g, const float* __restrict__ ln1b,
               const void* __restrict__ w1,   const float* __restrict__ b1,
               const void* __restrict__ w2,   const float* __restrict__ b2,
               const float* __restrict__ ln2g, const float* __restrict__ ln2b,
               float* __restrict__ out)
{
  extern __shared__ char smem[];
  const int tid = threadIdx.x;
  const int win = tid >> 9;            // this thread's window (attention/LN phases)
  const int gw  = tid >> 6;            // global wave 0..15 (weight-GEMM phases)
  const int wv  = gw & 7;              // wave within window (attention)
  const int l   = tid & 63;
  const int cl  = l & 15, kg = l >> 4;

  unsigned short* alnW[2]; char* poolW[2];
  #pragma unroll
  for (int w = 0; w < 2; ++w) {
    alnW[w]  = (unsigned short*)(smem + w * ALN_SZ);
    poolW[w] = smem + POOL + w * PS;
  }
  unsigned short* aln = alnW[win];
  char* pool = poolW[win];
  unsigned short* q2  = (unsigned short*)(pool + Q2_OFF);
  unsigned short* k2  = (unsigned short*)(pool + K2_OFF);
  unsigned short* vT2 = (unsigned short*)(pool + VT_OFF);
  unsigned short* oh  = (unsigned short*)(pool + OH_OFF);

  const int wid0 = blockIdx.x * 2;
  auto gidxw = [&](int w, int r, int c) -> size_t {
    int wid = wid0 + w;
    int iw = wid & 7, ih = (wid >> 3) & 7, bt = wid >> 6;
    int wi = r / 7, wj = r - wi * 7;
    return ((size_t)bt * 3136 + (size_t)((ih*7 + wi) * 56 + iw*7 + wj)) * 384 + c;
  };

  auto ln_pass = [&](const float* src, const float* gw_, const float* gb_) {
    int row = (tid >> 3) & 63, lj = tid & 7;
    if (row < 49) {
      size_t base = gidxw(win, row, 0);
      float4 xv[12];
      float sx = 0.f, sxx = 0.f;
      #pragma unroll
      for (int k = 0; k < 12; ++k) {
        xv[k] = *(const float4*)&src[base + (lj + 8*k) * 4];
        sx  += xv[k].x + xv[k].y + xv[k].z + xv[k].w;
        sxx += xv[k].x*xv[k].x + xv[k].y*xv[k].y + xv[k].z*xv[k].z + xv[k].w*xv[k].w;
      }
      #pragma unroll
      for (int d = 1; d < 8; d <<= 1) { sx += __shfl_xor(sx, d, 8); sxx += __shfl_xor(sxx, d, 8); }
      float mean = sx * (1.f/384.f);
      float rs = rsqrtf(sxx * (1.f/384.f) - mean*mean + 1e-5f);
      unsigned short* arow = aln + row * ALN_STR;
      #pragma unroll
      for (int k = 0; k < 12; ++k) {
        int c = (lj + 8*k) * 4;
        float4 gv = *(const float4*)&gw_[c];
        float4 bv = *(const float4*)&gb_[c];
        unsigned u0 = pk2((xv[k].x-mean)*rs*gv.x + bv.x, (xv[k].y-mean)*rs*gv.y + bv.y);
        unsigned u1 = pk2((xv[k].z-mean)*rs*gv.z + bv.z, (xv[k].w-mean)*rs*gv.w + bv.w);
        *(uint2*)&arow[c] = make_uint2(u0, u1);
      }
    }
  };

  const int ri = gw & 3;               // weight-GEMM row-tile
  const int cg = gw >> 2;              // weight-GEMM col-group (0..3)
  const int arowA = (cl + 16 * ri) * ALN_STR;

  // QKV for head pair pr, BOTH windows (B loaded once): role (ri, 3 cols, 2 win)
  auto qkv = [&](int pr) {
    int tile[3], grow[3], part[3], wt[3];
    #pragma unroll
    for (int j = 0; j < 3; ++j) {
      int ci = cg * 3 + j;
      part[j] = ci >> 2; wt[j] = ci & 3;
      tile[j] = part[j] * 24 + pr * 4 + wt[j];
      grow[j] = part[j] * 384 + pr * 64 + wt[j] * 16 + cl;
    }
    f32x4 d00{0,0,0,0}, d01{0,0,0,0}, d02{0,0,0,0};
    f32x4 d10{0,0,0,0}, d11{0,0,0,0}, d12{0,0,0,0};
    #pragma unroll
    for (int kt = 0; kt < 12; ++kt) {
      int k0 = kt * 32 + kg * 8;
      short8 wb0 = loadW<WBF>(ipw, tile[0], 48, kt*4, l, grow[0], 384, k0);
      short8 wb1 = loadW<WBF>(ipw, tile[1], 48, kt*4, l, grow[1], 384, k0);
      short8 wb2 = loadW<WBF>(ipw, tile[2], 48, kt*4, l, grow[2], 384, k0);
      short8 a0 = *(const short8*)&alnW[0][arowA + k0];
      short8 a1 = *(const short8*)&alnW[1][arowA + k0];
      d00 = MFMA_B16(a0, wb0, d00); d01 = MFMA_B16(a0, wb1, d01); d02 = MFMA_B16(a0, wb2, d02);
      d10 = MFMA_B16(a1, wb0, d10); d11 = MFMA_B16(a1, wb1, d11); d12 = MFMA_B16(a1, wb2, d12);
    }
    #pragma unroll
    for (int w = 0; w < 2; ++w) {
      unsigned short* q2w = (unsigned short*)(poolW[w] + Q2_OFF);
      unsigned short* k2w = (unsigned short*)(poolW[w] + K2_OFF);
      unsigned short* vTw = (unsigned short*)(poolW[w] + VT_OFF);
      #pragma unroll
      for (int j = 0; j < 3; ++j) {
        f32x4 dd = (w == 0) ? (j == 0 ? d00 : j == 1 ? d01 : d02)
                            : (j == 0 ? d10 : j == 1 ? d11 : d12);
        float bias = ipb[grow[j]];
        float scl = (part[j] == 0) ? 0.17677669529663687f : 1.f;
        int within = wt[j] * 16 + cl;
        #pragma unroll
        for (int rg = 0; rg < 4; ++rg) {
          int row = kg * 4 + rg + 16 * ri;
          if (row < 49) {
            unsigned short bv = f2bfu((dd[rg] + bias) * scl);
            if      (part[j] == 0) q2w[row * QK_STR + within] = bv;
            else if (part[j] == 1) k2w[row * QK_STR + within] = bv;
            else                   vTw[within * VT_STR + row] = bv;
          }
        }
      }
    }
  };

  // ---- init: zero vT2 pad (token cols >=49 must stay 0), LN1 ----
  for (int i = (tid & 511); i < (64*VT_STR)/2; i += 512)
    ((unsigned*)(pool + VT_OFF))[i] = 0u;
  ln_pass(tokens, ln1g, ln1b);
  __syncthreads();

  f32x4 opacc[2][6];
  #pragma unroll
  for (int a = 0; a < 2; ++a)
    #pragma unroll
    for (int b = 0; b < 6; ++b) opacc[a][b] = f32x4{0.f,0.f,0.f,0.f};

  qkv(0);
  __syncthreads();

  const int hl = wv & 1, qci = wv >> 1;   // wave's (head-within-pair, q col-tile)

  for (int pr = 0; pr < 6; ++pr) {
    // ---- P_a: scores (swapped: mfma(K,Q)) + in-register softmax + PV ----
    {
      short8 bq = *(const short8*)&q2[(16*qci + cl) * QK_STR + hl*32 + kg*8];
      f32x4 dsc[4];
      #pragma unroll
      for (int kri = 0; kri < 4; ++kri) {
        short8 ak = *(const short8*)&k2[(16*kri + cl) * QK_STR + hl*32 + kg*8];
        f32x4 z{0.f,0.f,0.f,0.f};
        dsc[kri] = MFMA_B16(ak, bq, z);
      }
      float ev[4][4];
      float mx = -1e30f;
      #pragma unroll
      for (int kri = 0; kri < 4; ++kri)
        #pragma unroll
        for (int r = 0; r < 4; ++r) {
          int kidx = 16*kri + 4*kg + r;
          float v = (kidx < 49) ? dsc[kri][r] : -1e30f;
          ev[kri][r] = v;
          mx = fmaxf(mx, v);
        }
      mx = fmaxf(mx, __shfl_xor(mx, 16));
      mx = fmaxf(mx, __shfl_xor(mx, 32));
      float sum = 0.f;
      #pragma unroll
      for (int kri = 0; kri < 4; ++kri)
        #pragma unroll
        for (int r = 0; r < 4; ++r) {
          float e = __expf(ev[kri][r] - mx);
          ev[kri][r] = e; sum += e;
        }
      sum += __shfl_xor(sum, 16);
      sum += __shfl_xor(sum, 32);
      float inv = 1.f / sum;
      unsigned pk[4][2];
      #pragma unroll
      for (int kri = 0; kri < 4; ++kri) {
        pk[kri][0] = pk2(ev[kri][0]*inv, ev[kri][1]*inv);
        pk[kri][1] = pk2(ev[kri][2]*inv, ev[kri][3]*inv);
      }
      f32x4 dot0{0.f,0.f,0.f,0.f}, dot1{0.f,0.f,0.f,0.f};
      const int sA = cl + 32 * (kg & 1);
      const bool hi = (kg >> 1) & 1;
      #pragma unroll
      for (int kt = 0; kt < 2; ++kt) {
        unsigned x0 = (unsigned)__shfl((int)pk[2*kt][0],   sA);
        unsigned x1 = (unsigned)__shfl((int)pk[2*kt][1],   sA);
        unsigned x2 = (unsigned)__shfl((int)pk[2*kt][0],   sA + 16);
        unsigned x3 = (unsigned)__shfl((int)pk[2*kt][1],   sA + 16);
        unsigned y0 = (unsigned)__shfl((int)pk[2*kt+1][0], sA);
        unsigned y1 = (unsigned)__shfl((int)pk[2*kt+1][1], sA);
        unsigned y2 = (unsigned)__shfl((int)pk[2*kt+1][0], sA + 16);
        unsigned y3 = (unsigned)__shfl((int)pk[2*kt+1][1], sA + 16);
        uint4 bu = make_uint4(hi ? y0 : x0, hi ? y1 : x1, hi ? y2 : x2, hi ? y3 : x3);
        short8 bfrag = *(short8*)&bu;
        short8 a0 = *(const short8*)&vT2[(hl*32 +  0 + cl) * VT_STR + kt*32 + kg*8];
        short8 a1 = *(const short8*)&vT2[(hl*32 + 16 + cl) * VT_STR + kt*32 + kg*8];
        dot0 = MFMA_B16(a0, bfrag, dot0);
        dot1 = MFMA_B16(a1, bfrag, dot1);
      }
      int q = 16*qci + cl;
      if (q < 49) {
        int base = q * OH_STR + hl*32 + kg*4;
        *(unsigned*)&oh[base     ] = pk2(dot0[0], dot0[1]);
        *(unsigned*)&oh[base +  2] = pk2(dot0[2], dot0[3]);
        *(unsigned*)&oh[base + 16] = pk2(dot1[0], dot1[1]);
        *(unsigned*)&oh[base + 18] = pk2(dot1[2], dot1[3]);
      }
    }
    __syncthreads();

    // ---- P_b: out-proj(pr) both windows (B once) + QKV(pr+1) ----
    {
      short8 ao[2][2];
      #pragma unroll
      for (int w = 0; w < 2; ++w) {
        unsigned short* ohw = (unsigned short*)(poolW[w] + OH_OFF);
        ao[w][0] = *(const short8*)&ohw[(cl + 16*ri) * OH_STR +      kg*8];
        ao[w][1] = *(const short8*)&ohw[(cl + 16*ri) * OH_STR + 32 + kg*8];
      }
      #pragma unroll
      for (int j = 0; j < 6; ++j) {
        int ct = cg*6 + j;
        short8 bw0 = loadW<WBF>(outw, ct, 48, pr*8,     l, ct*16 + cl, 384, pr*64      + kg*8);
        short8 bw1 = loadW<WBF>(outw, ct, 48, pr*8 + 4, l, ct*16 + cl, 384, pr*64 + 32 + kg*8);
        opacc[0][j] = MFMA_B16(ao[0][0], bw0, opacc[0][j]);
        opacc[0][j] = MFMA_B16(ao[0][1], bw1, opacc[0][j]);
        opacc[1][j] = MFMA_B16(ao[1][0], bw0, opacc[1][j]);
        opacc[1][j] = MFMA_B16(ao[1][1], bw1, opacc[1][j]);
      }
      if (pr < 5) qkv(pr + 1);
    }
    __syncthreads();
  }

  // ---- win = tokens + attn + out_b -> out (role: ri x 6 cols x 2 win) ----
  #pragma unroll
  for (int w = 0; w < 2; ++w)
    #pragma unroll
    for (int j = 0; j < 6; ++j) {
      int col = (cg*6 + j) * 16 + cl;
      float ob = outb[col];
      #pragma unroll
      for (int rg = 0; rg < 4; ++rg) {
        int row = 16*ri + kg*4 + rg;
        if (row < 49) {
          size_t g = gidxw(w, row, col);
          out[g] = tokens[g] + opacc[w][j][rg] + ob;
        }
      }
    }
  __syncthreads();

  // ---- LN2 ----
  ln_pass(out, ln2g, ln2b);
  __syncthreads();

  // ---- MLP: cross-window roles, hid double-buffered ----
  f32x4 macc[2][2][3];
  #pragma unroll
  for (int a = 0; a < 2; ++a)
    #pragma unroll
    for (int t = 0; t < 2; ++t)
      #pragma unroll
      for (int j = 0; j < 3; ++j) macc[a][t][j] = f32x4{0.f,0.f,0.f,0.f};

  const int rp = gw & 1, cg3 = gw >> 1;   // MLP2 role: rows {2rp,2rp+1}, cols cg3*3..+2

  // MLP1(cc): role (ri, 2 cols, 2 win); A from LDS (1 read/kt/win), B exclusive-ish
  auto mlp1 = [&](int cc, int pb) {
    f32x4 e00{0,0,0,0}, e01{0,0,0,0}, e10{0,0,0,0}, e11{0,0,0,0};
    #pragma unroll
    for (int kt = 0; kt < 12; ++kt) {
      int k0 = kt * 32 + kg * 8;
      short8 wb0 = loadW<WBF>(w1, cc*8 + cg*2 + 0, 48, kt*4, l, (cc*8+cg*2+0)*16 + cl, 384, k0);
      short8 wb1 = loadW<WBF>(w1, cc*8 + cg*2 + 1, 48, kt*4, l, (cc*8+cg*2+1)*16 + cl, 384, k0);
      short8 a0 = *(const short8*)&alnW[0][arowA + k0];
      short8 a1 = *(const short8*)&alnW[1][arowA + k0];
      e00 = MFMA_B16(a0, wb0, e00); e01 = MFMA_B16(a0, wb1, e01);
      e10 = MFMA_B16(a1, wb0, e10); e11 = MFMA_B16(a1, wb1, e11);
    }
    #pragma unroll
    for (int w = 0; w < 2; ++w) {
      unsigned short* hb = (unsigned short*)(poolW[w] + pb * HIDB);
      #pragma unroll
      for (int j = 0; j < 2; ++j) {
        f32x4 ee = (w == 0) ? (j == 0 ? e00 : e01) : (j == 0 ? e10 : e11);
        int n = cc*128 + (cg*2 + j)*16 + cl;
        float bb = b1[n];
        #pragma unroll
        for (int rg = 0; rg < 4; ++rg) {
          int row = 16*ri + kg*4 + rg;
          if (row < 49) {
            float x = ee[rg] + bb;
            // gelu(x) ~= x * sigmoid(1.5957691(x + 0.044715 x^3))
            float t2 = 0.044715f * x * x;
            float arg = __builtin_fmaf(t2, x, x);
            float e = __expf(1.5957691216f * arg);
            float gl = x * (e / (e + 1.f));
            hb[row * HID_STR + (cg*2 + j)*16 + cl] = f2bfu(gl);
          }
        }
      }
    }
  };
  // MLP2(cc): role (2 rows, 3 cols, 2 win), K=128
  auto mlp2 = [&](int cc, int pb) {
    unsigned short* hb0 = (unsigned short*)(poolW[0] + pb * HIDB);
    unsigned short* hb1 = (unsigned short*)(poolW[1] + pb * HIDB);
    #pragma unroll
    for (int kt = 0; kt < 4; ++kt) {
      int k0 = kt * 32 + kg * 8;
      short8 hd00 = *(const short8*)&hb0[(cl + 16*(2*rp    )) * HID_STR + k0];
      short8 hd01 = *(const short8*)&hb0[(cl + 16*(2*rp + 1)) * HID_STR + k0];
      short8 hd10 = *(const short8*)&hb1[(cl + 16*(2*rp    )) * HID_STR + k0];
      short8 hd11 = *(const short8*)&hb1[(cl + 16*(2*rp + 1)) * HID_STR + k0];
      #pragma unroll
      for (int j = 0; j < 3; ++j) {
        int ct = cg3*3 + j;
        short8 bw = loadW<WBF>(w2, ct, 192, cc*16 + kt*4, l,
                               ct*16 + cl, 1536, cc*128 + k0);
        macc[0][0][j] = MFMA_B16(hd00, bw, macc[0][0][j]);
        macc[0][1][j] = MFMA_B16(hd01, bw, macc[0][1][j]);
        macc[1][0][j] = MFMA_B16(hd10, bw, macc[1][0][j]);
        macc[1][1][j] = MFMA_B16(hd11, bw, macc[1][1][j]);
      }
    }
  };

  mlp1(0, 0);
  __syncthreads();
  for (int cc = 1; cc < 12; ++cc) {
    mlp2(cc - 1, (cc - 1) & 1);
    mlp1(cc, cc & 1);
    __syncthreads();
  }
  mlp2(11, 1);

  // ---- final: out += mlp + b2 (role: rows {2rp,2rp+1} x 3 cols x 2 win) ----
  #pragma unroll
  for (int w = 0; w < 2; ++w)
    #pragma unroll
    for (int t = 0; t < 2; ++t)
      #pragma unroll
      for (int j = 0; j < 3; ++j) {
        int col = (cg3*3 + j) * 16 + cl;
        float bb2 = b2[col];
        #pragma unroll
        for (int rg = 0; rg < 4; ++rg) {
          int row = 16*(2*rp + t) + kg*4 + rg;
          if (row < 49) {
            size_t g = gidxw(w, row, col);
            out[g] = out[g] + macc[w][t][j][rg] + bb2;
          }
        }
      }
}

// ws layout (bf16 elements): ipw[442368] | outw[147456] | w1[589824] | w2[589824]
#define WS_IPW  0
#define WS_OUTW 442368
#define WS_W1   589824
#define WS_W2   1179648
#define WS_TOT  1769472

extern "C" void kernel_launch(void* const* d_in, const int* in_sizes, int n_in,
                              void* d_out, int out_size, void* d_ws, size_t ws_size,
                              hipStream_t stream) {
  (void)in_sizes; (void)n_in; (void)out_size;
  const float* tokens = (const float*)d_in[0];
  const float* ipw  = (const float*)d_in[1];
  const float* ipb  = (const float*)d_in[2];
  const float* outw = (const float*)d_in[3];
  const float* outb = (const float*)d_in[4];
  const float* ln1g = (const float*)d_in[5];
  const float* ln1b = (const float*)d_in[6];
  const float* w1   = (const float*)d_in[7];
  const float* b1   = (const float*)d_in[8];
  const float* w2   = (const float*)d_in[9];
  const float* b2   = (const float*)d_in[10];
  const float* ln2g = (const float*)d_in[11];
  const float* ln2b = (const float*)d_in[12];
  float* out = (float*)d_out;

  bool wbf = (ws_size >= (size_t)WS_TOT * 2);
  if (wbf) {
    unsigned short* wsp = (unsigned short*)d_ws;
    hipLaunchKernelGGL(cvt_pack, dim3((442368+511)/512), dim3(512), 0, stream, ipw,  wsp + WS_IPW,  384,  442368);
    hipLaunchKernelGGL(cvt_pack, dim3((147456+511)/512), dim3(512), 0, stream, outw, wsp + WS_OUTW, 384,  147456);
    hipLaunchKernelGGL(cvt_pack, dim3((589824+511)/512), dim3(512), 0, stream, w1,   wsp + WS_W1,   384,  589824);
    hipLaunchKernelGGL(cvt_pack, dim3((589824+511)/512), dim3(512), 0, stream, w2,   wsp + WS_W2,   1536, 589824);
    (void)hipFuncSetAttribute((const void*)swin_mfma<true>,
                              hipFuncAttributeMaxDynamicSharedMemorySize, SMEM_BYTES);
    hipLaunchKernelGGL((swin_mfma<true>), dim3(512), dim3(1024), SMEM_BYTES, stream,
                       tokens, (const void*)(wsp + WS_IPW), ipb,
                       (const void*)(wsp + WS_OUTW), outb, ln1g, ln1b,
                       (const void*)(wsp + WS_W1), b1, (const void*)(wsp + WS_W2), b2,
                       ln2g, ln2b, out);
  } else {
    (void)hipFuncSetAttribute((const void*)swin_mfma<false>,
                              hipFuncAttributeMaxDynamicSharedMemorySize, SMEM_BYTES);
    hipLaunchKernelGGL((swin_mfma<false>), dim3(512), dim3(1024), SMEM_BYTES, stream,
                       tokens, (const void*)ipw, ipb, (const void*)outw, outb, ln1g, ln1b,
                       (const void*)w1, b1, (const void*)w2, b2, ln2g, ln2b, out);
  }
}